// Round 8
// baseline (116.519 us; speedup 1.0000x reference)
//
#include <hip/hip_runtime.h>
#include <hip/hip_bf16.h>
#include <math.h>

// S5 SSM layer. B_SZ=16, L=1024, H=256, P=256.
// 4 dispatches:
//   k_prep     : W1T, W2T, PW table, u->UB (bf16)
//   k_g1scan   : BM=128 x BN=128 GEMM1 (all-DMA staging) -> LDS X -> scan 4 chunks -> XS + CEND
//   k_carry    : exclusive chunk-carry prefix CEND -> CARR (16 blocks)
//   k_gemm2fix : GEMM2 with carry fixup folded into A-staging (BK=64) + D*u
#define BB     16
#define LSEQ   1024
#define HH     256
#define PP     256
#define MROWS  (BB*LSEQ)     // 16384
#define LC     32
#define NC     (LSEQ/LC)     // 32
#define NCHUNK (BB*NC)       // 512

// workspace byte offsets
#define OFF_W1T  0u          // [512][256] bf16: row 2p=Re(B_bar[p][.]), 2p+1=Im
#define OFF_W2T  262144u     // [256][512] bf16: row h, k=2p -> 2*C_re, 2p+1 -> -2*C_im
#define OFF_PW   524288u     // [33][256] float2: lambda_bar^t
#define OFF_CEND 655360u     // [512][256] float2 chunk-end local states
#define OFF_CARR 1703936u    // [512][256] float2 exclusive chunk carries
#define OFF_XS   2752512u    // [16384][512] bf16 x_local (col 2p=re, 2p+1=im)
#define OFF_UB   19529728u   // [16384][256] bf16 u
// total ~26.6 MB

typedef __attribute__((ext_vector_type(8))) short short8;
typedef __attribute__((ext_vector_type(4))) float floatx4;

__device__ __forceinline__ float bf2f(unsigned hs) {
    union { unsigned u; float f; } v; v.u = hs << 16; return v.f;
}
__device__ __forceinline__ unsigned short f2bs(float f) {
    __hip_bfloat16 h = __float2bfloat16(f);
    union { __hip_bfloat16 h; unsigned short s; } v; v.h = h; return v.s;
}
__device__ __forceinline__ unsigned packbf(float r, float i) {
    return (unsigned)f2bs(r) | ((unsigned)f2bs(i) << 16);
}
__device__ __forceinline__ void async16(const void* g, void* l) {
    __builtin_amdgcn_global_load_lds(
        (const __attribute__((address_space(1))) unsigned*)g,
        (__attribute__((address_space(3))) unsigned*)l, 16, 0, 0);
}
__device__ __forceinline__ float2 lam_pow(float lr, float li, float dtt) {
    float m = expf(lr * dtt);
    return make_float2(m * cosf(li * dtt), m * sinf(li * dtt));
}

// ---------------- prep: W1T/PW (blocks 0..255), W2T (256..511), u->UB (all) ----------------
__global__ void k_prep(const float* __restrict__ Bm, const float* __restrict__ Cm,
                       const float* __restrict__ Lr, const float* __restrict__ Li,
                       const float* __restrict__ ls, const float* __restrict__ u,
                       char* __restrict__ ws) {
    int blk = blockIdx.x, t = threadIdx.x;
    if (blk < 256) {
        int p = blk, h = t;
        float lr = Lr[p], li = Li[p];
        float dt = expf(ls[p]);
        float2 lam = lam_pow(lr, li, dt);
        float den = lr * lr + li * li;
        float nr = lam.x - 1.0f, ni = lam.y;
        float cr = (nr * lr + ni * li) / den;       // (lam_bar-1)/Lambda
        float ci = (ni * lr - nr * li) / den;
        float br = Bm[(p * HH + h) * 2 + 0];
        float bi = Bm[(p * HH + h) * 2 + 1];
        unsigned short* w1 = (unsigned short*)(ws + OFF_W1T);
        w1[(2 * p) * 256 + h]     = f2bs(cr * br - ci * bi);
        w1[(2 * p + 1) * 256 + h] = f2bs(cr * bi + ci * br);
        if (t <= 32)   // lambda power table pw[t][p]
            ((float2*)(ws + OFF_PW))[t * 256 + p] = lam_pow(lr, li, dt * (float)t);
    } else {
        int h = blk - 256, p = t;
        float c_r = Cm[(h * PP + p) * 2 + 0];
        float c_i = Cm[(h * PP + p) * 2 + 1];
        ((unsigned*)(ws + OFF_W2T))[h * 256 + p] = packbf(2.0f * c_r, -2.0f * c_i);
    }
    // u -> UB (bf16): 1048576 float4 total, 2048 per block, 8 per thread
    uint2* ub = (uint2*)(ws + OFF_UB);
    const float4* u4 = (const float4*)u;
    #pragma unroll
    for (int i = 0; i < 8; ++i) {
        size_t idx = (size_t)blk * 2048 + i * 256 + t;
        float4 v = u4[idx];
        ub[idx] = make_uint2(packbf(v.x, v.y), packbf(v.z, v.w));
    }
}

// ---------------- GEMM1 (BM=128 x BN=128, BK=64, all-DMA) + 4-chunk scan ----------------
// grid 512 = 128 row-groups x 4 N-slices; 512 threads (8 waves, 1 N-tile each).
#define XSTR 140    // bf16 stride of LDS X rows (140/2=70 banks: q-groups spread, no conflict)
__global__ __launch_bounds__(512, 2) void k_g1scan(
        const float* __restrict__ Lr, const float* __restrict__ Li,
        const float* __restrict__ ls, char* __restrict__ ws) {
    __shared__ char smem[36864];
    char* Asb = smem;                 // [2][128][32] bf16 (8 KB/panel)
    char* Bsb = smem + 16384;         // [2][128][32] bf16
    unsigned short* X = (unsigned short*)smem;   // [128][XSTR] (after GEMM)
    unsigned* X32 = (unsigned*)smem;             // stride XSTR/2
    const unsigned short* W1 = (const unsigned short*)(ws + OFF_W1T);
    const unsigned short* UB = (const unsigned short*)(ws + OFF_UB);
    const int tid = threadIdx.x, bx = blockIdx.x;
    const int ns = bx & 3, rg = bx >> 2;
    const int m0 = rg * 128, n0 = ns * 128;
    const int wave = tid >> 6, lane = tid & 63;
    const int q = lane >> 4, rr = lane & 15;
    const int c4 = lane & 3, r4 = lane >> 2;

    floatx4 acc[8];
    #pragma unroll
    for (int i = 0; i < 8; ++i) acc[i] = (floatx4)0.0f;

    for (int k0 = 0; k0 < 256; k0 += 64) {
        __syncthreads();
        #pragma unroll
        for (int t = 0; t < 2; ++t) {               // 16 row-panel groups over 8 waves
            int idx = t * 8 + wave;
            int pan = idx & 1, rowg = idx >> 1;     // rowg 0..7
            int row = rowg * 16 + r4;
            async16(UB + (size_t)(m0 + row) * 256 + k0 + pan * 32 + c4 * 8,
                    Asb + pan * 8192 + row * 64 + c4 * 16);
            async16(W1 + (size_t)(n0 + row) * 256 + k0 + pan * 32 + c4 * 8,
                    Bsb + pan * 8192 + row * 64 + c4 * 16);
        }
        __syncthreads();
        #pragma unroll
        for (int ks = 0; ks < 2; ++ks) {
            short8 b = *(const short8*)(Bsb + ks * 8192 + (wave * 16 + rr) * 64 + q * 16);
            #pragma unroll
            for (int i = 0; i < 8; ++i) {
                short8 a = *(const short8*)(Asb + ks * 8192 + (i * 16 + rr) * 64 + q * 16);
                acc[i] = __builtin_amdgcn_mfma_f32_16x16x32_bf16(a, b, acc[i], 0, 0, 0);
            }
        }
    }
    __syncthreads();
    // dump Bu tile (128 x 128) into LDS X; wave covers local cols wave*16..+15
    #pragma unroll
    for (int i = 0; i < 8; ++i)
        #pragma unroll
        for (int r0 = 0; r0 < 4; ++r0)
            X[(i * 16 + q * 4 + r0) * XSTR + wave * 16 + rr] = f2bs(acc[i][r0]);
    __syncthreads();

    // scan: 256 units = 4 chunks x 64 local pairs
    if (tid < 256) {
        const int ch = tid >> 6, pq = tid & 63;
        const int gp = (n0 >> 1) + pq;                 // global channel pair
        const float2 lam = lam_pow(Lr[gp], Li[gp], expf(ls[gp]));
        unsigned* xs32 = (unsigned*)(ws + OFF_XS);
        float xr = 0.0f, xi = 0.0f;
        for (int j = 0; j < LC; ++j) {
            unsigned cv = X32[(ch * 32 + j) * (XSTR / 2) + pq];
            float br = bf2f(cv & 0xffffu), bi = bf2f(cv >> 16);
            float nr = fmaf(lam.x, xr, fmaf(-lam.y, xi, br));
            float ni = fmaf(lam.x, xi, fmaf(lam.y, xr, bi));
            xr = nr; xi = ni;
            xs32[(size_t)(m0 + ch * 32 + j) * 256 + gp] = packbf(xr, xi);
        }
        ((float2*)(ws + OFF_CEND))[(size_t)(rg * 4 + ch) * 256 + gp] = make_float2(xr, xi);
    }
}

// ---------------- carry: exclusive prefix of chunk carries (16 blocks) ----------------
__global__ void k_carry(const float* __restrict__ Lr, const float* __restrict__ Li,
                        const float* __restrict__ ls, char* __restrict__ ws) {
    int p = threadIdx.x, b = blockIdx.x;
    float dt = expf(ls[p]);
    float2 g = lam_pow(Lr[p], Li[p], dt * (float)LC);   // lambda^LC
    const float2* cend = (const float2*)(ws + OFF_CEND);
    float2* carr = (float2*)(ws + OFF_CARR);
    float sr = 0.0f, si = 0.0f;
    for (int c = 0; c < NC; ++c) {
        size_t off = (size_t)(b * NC + c) * 256 + p;
        carr[off] = make_float2(sr, si);
        float2 e = cend[off];
        float nr = fmaf(g.x, sr, fmaf(-g.y, si, e.x));
        float ni = fmaf(g.x, si, fmaf(g.y, sr, e.y));
        sr = nr; si = ni;
    }
}

// ---------------- GEMM2 with inline carry fixup (BK=64 two-panel) ----------------
// out = (x_local + lam^{j+1}*carry) @ W2T^T + D*u. BM=64, BN=128, grid (2,256).
__global__ __launch_bounds__(256, 4) void k_gemm2fix(
        const char* __restrict__ ws_c, const float* __restrict__ D,
        const float* __restrict__ u, float* __restrict__ out) {
    __shared__ char Asb[8192];          // [2][64][32] bf16
    __shared__ char Bsb[16384];         // [2][128][32] bf16
    __shared__ float2 carrs[2][256];    // this block's 2 chunk carries
    const unsigned short* W2 = (const unsigned short*)(ws_c + OFF_W2T);
    const unsigned* xs32 = (const unsigned*)(ws_c + OFF_XS);
    const float2* pw = (const float2*)(ws_c + OFF_PW);
    const float2* carr = (const float2*)(ws_c + OFF_CARR);

    const int tid = threadIdx.x;
    const int wave = tid >> 6, lane = tid & 63;
    const int q = lane >> 4, rr = lane & 15;
    const int c4 = lane & 3, r4 = lane >> 2;
    const int wm = wave & 1, wn = wave >> 1;
    const int m0 = blockIdx.y * 64, n0 = blockIdx.x * 128;

    {   // stage this block's carries (chunks m0/32 and m0/32+1)
        int cbase = m0 >> 5;
        carrs[0][tid] = carr[(size_t)cbase * 256 + tid];
        carrs[1][tid] = carr[(size_t)(cbase + 1) * 256 + tid];
    }

    floatx4 acc[2][4];
    #pragma unroll
    for (int i = 0; i < 2; ++i)
        #pragma unroll
        for (int j = 0; j < 4; ++j) acc[i][j] = (floatx4)0.0f;

    const int row = tid >> 2, qd = tid & 3;    // staging: 8 pairs/thread/iter
    const int grow = m0 + row;
    const int jj = (grow & (LC - 1)) + 1;
    const int half = row >> 5;

    for (int k0 = 0; k0 < 512; k0 += 64) {
        __syncthreads();   // publishes carrs on first iteration
        {
            int p0 = (k0 >> 1) + qd * 8;
            uint4 xa = *(const uint4*)(xs32 + (size_t)grow * 256 + p0);
            uint4 xb = *(const uint4*)(xs32 + (size_t)grow * 256 + p0 + 4);
            unsigned xv[8] = {xa.x, xa.y, xa.z, xa.w, xb.x, xb.y, xb.z, xb.w};
            const float2* pwp = pw + (size_t)jj * 256 + p0;
            const float2* cap = &carrs[half][p0];
            unsigned o[8];
            #pragma unroll
            for (int e = 0; e < 8; ++e) {
                float2 pwv = pwp[e];
                float2 cav = cap[e];
                float fr = pwv.x * cav.x - pwv.y * cav.y;
                float fi = pwv.x * cav.y + pwv.y * cav.x;
                o[e] = packbf(bf2f(xv[e] & 0xffffu) + fr, bf2f(xv[e] >> 16) + fi);
            }
            char* dst = Asb + (qd >> 1) * 4096 + row * 64 + (qd & 1) * 32;
            *(uint4*)dst        = make_uint4(o[0], o[1], o[2], o[3]);
            *(uint4*)(dst + 16) = make_uint4(o[4], o[5], o[6], o[7]);
        }
        #pragma unroll
        for (int t = 0; t < 4; ++t) {          // Bs: 128 rows x 2 panels
            int idx = t * 4 + wave;
            int pan = idx & 1, rowg = idx >> 1;
            int rw = rowg * 16 + r4;
            async16(W2 + (size_t)(n0 + rw) * 512 + k0 + pan * 32 + c4 * 8,
                    Bsb + pan * 8192 + rw * 64 + c4 * 16);
        }
        __syncthreads();
        #pragma unroll
        for (int ks = 0; ks < 2; ++ks) {
            short8 a[2], bfr[4];
            #pragma unroll
            for (int i = 0; i < 2; ++i)
                a[i] = *(const short8*)(Asb + ks * 4096 +
                                        (wm * 32 + i * 16 + rr) * 64 + q * 16);
            #pragma unroll
            for (int j = 0; j < 4; ++j)
                bfr[j] = *(const short8*)(Bsb + ks * 8192 +
                                          ((wn * 64 + j * 16 + rr)) * 64 + q * 16);
            #pragma unroll
            for (int i = 0; i < 2; ++i)
                #pragma unroll
                for (int j = 0; j < 4; ++j)
                    acc[i][j] = __builtin_amdgcn_mfma_f32_16x16x32_bf16(a[i], bfr[j], acc[i][j], 0, 0, 0);
        }
    }

    #pragma unroll
    for (int i = 0; i < 2; ++i) {
        int mbase = m0 + wm * 32 + i * 16 + q * 4;
        #pragma unroll
        for (int j = 0; j < 4; ++j) {
            int col = n0 + wn * 64 + j * 16 + rr;
            #pragma unroll
            for (int r0 = 0; r0 < 4; ++r0) {
                int rw = mbase + r0;
                size_t gi = (size_t)rw * 256 + col;
                out[gi] = acc[i][j][r0] + D[col] * u[gi];
            }
        }
    }
}

extern "C" void kernel_launch(void* const* d_in, const int* in_sizes, int n_in,
                              void* d_out, int out_size, void* d_ws, size_t ws_size,
                              hipStream_t stream) {
    const float* u  = (const float*)d_in[0];
    const float* Lr = (const float*)d_in[1];
    const float* Li = (const float*)d_in[2];
    const float* Bm = (const float*)d_in[3];
    const float* Cm = (const float*)d_in[4];
    const float* D  = (const float*)d_in[5];
    const float* ls = (const float*)d_in[6];
    float* out = (float*)d_out;
    char* ws = (char*)d_ws;

    k_prep<<<512, 256, 0, stream>>>(Bm, Cm, Lr, Li, ls, u, ws);
    k_g1scan<<<512, 512, 0, stream>>>(Lr, Li, ls, ws);
    k_carry<<<BB, 256, 0, stream>>>(Lr, Li, ls, ws);
    k_gemm2fix<<<dim3(2, MROWS / 64), 256, 0, stream>>>(ws, D, u, out);
}